// Round 6
// baseline (42145.706 us; speedup 1.0000x reference)
//
#include <hip/hip_runtime.h>

#define Tq 256
#define Sq 512
#define Hq 512
#define H2q 1024
#define KPACK 1664   // trg(128) | outs(512) | ctx(1024)

__device__ __forceinline__ float bf2f(ushort u){ return __uint_as_float(((unsigned)u)<<16); }
__device__ __forceinline__ ushort f2bf(float f){
  unsigned u = __float_as_uint(f);
  u += 0x7FFFu + ((u>>16)&1u);
  return (ushort)(u>>16);
}
__device__ __forceinline__ float frcp(float x){ return __builtin_amdgcn_rcpf(x); }
__device__ __forceinline__ float ftanh(float x){
  x = fminf(fmaxf(x, -15.f), 15.f);
  float u = __expf(x + x);
  return (u - 1.f) * frcp(u + 1.f);
}
__device__ __forceinline__ float fsig(float x){
  return frcp(1.f + __expf(-x));
}

typedef __attribute__((ext_vector_type(8))) short short8_t;
typedef __attribute__((ext_vector_type(4))) float f32x4;

// ---------------- guard bail (f32 out) ----------------
__global__ void bail_kernel(float* out, float v){
  if (threadIdx.x < 256) out[threadIdx.x] = v;
}

// ---------------- conversion kernels ----------------
__global__ void conv_bf16(const float* __restrict__ src, ushort* __restrict__ dst, int n4){
  int idx = blockIdx.x*blockDim.x + threadIdx.x;
  if (idx >= n4) return;
  float4 v = ((const float4*)src)[idx];
  ushort4 o; o.x = f2bf(v.x); o.y = f2bf(v.y); o.z = f2bf(v.z); o.w = f2bf(v.w);
  ((ushort4*)dst)[idx] = o;
}

__global__ void pack_trg(const float* __restrict__ trg, ushort* __restrict__ packed, int n4){
  int idx = blockIdx.x*blockDim.x + threadIdx.x;
  if (idx >= n4) return;                 // n4 = B*T*E/4
  float4 v = ((const float4*)trg)[idx];
  int bt = idx >> 5, r = idx & 31;       // E/4 = 32
  ushort4 o; o.x = f2bf(v.x); o.y = f2bf(v.y); o.z = f2bf(v.z); o.w = f2bf(v.w);
  *(ushort4*)&packed[(long)bt*KPACK + r*4] = o;
}

__global__ void bsum_kernel(const float* __restrict__ a, const float* __restrict__ b,
                            float* __restrict__ o, int n){
  int idx = blockIdx.x*blockDim.x + threadIdx.x;
  if (idx < n) o[idx] = a[idx] + b[idx];
}

// ---------------- bridge ----------------
__global__ __launch_bounds__(512)
void bridge_kernel(const float* __restrict__ efh, const float* __restrict__ efc,
                   const float* __restrict__ bhw, const float* __restrict__ bhb,
                   const float* __restrict__ bcw, const float* __restrict__ bcb,
                   float* __restrict__ hb0, float* __restrict__ cws)
{
  int b = blockIdx.x, n = threadIdx.x;
  __shared__ __align__(16) float eh_l[1024];
  __shared__ __align__(16) float ec_l[1024];
  eh_l[n]       = efh[b*1024 + n];
  eh_l[n + 512] = efh[b*1024 + 512 + n];
  ec_l[n]       = efc[b*1024 + n];
  ec_l[n + 512] = efc[b*1024 + 512 + n];
  __syncthreads();
  const float4* wh = (const float4*)(bhw + (long)n*1024);
  const float4* wc = (const float4*)(bcw + (long)n*1024);
  float ah = bhb[n], ac = bcb[n];
  for (int i = 0; i < 256; ++i) {
    float4 w1 = wh[i]; float4 w2 = wc[i];
    const float* e1 = &eh_l[i*4]; const float* e2 = &ec_l[i*4];
    ah += w1.x*e1[0] + w1.y*e1[1] + w1.z*e1[2] + w1.w*e1[3];
    ac += w2.x*e2[0] + w2.y*e2[1] + w2.z*e2[2] + w2.w*e2[3];
  }
  hb0[b*512 + n] = ftanh(ah);
  cws[b*512 + n] = ftanh(ac);
}

// ---------------- MFMA BT-GEMM: C[m,n] = sum_k A[m,k]*Bt[n,k] ----------------
__global__ __launch_bounds__(256)
void gemm_bt(const ushort* __restrict__ A, int lda, long sA,
             const ushort* __restrict__ Bt, int ldb, long sB,
             void* __restrict__ Cout, int ldc, long sC, int K, int outBf16)
{
  __shared__ __align__(16) ushort Al[128][40];
  __shared__ __align__(16) ushort Bl[128][40];
  int bz = blockIdx.z;
  const ushort* Ab = A + (long)bz*sA;
  const ushort* Bb = Bt + (long)bz*sB;
  int m0 = blockIdx.x*128, n0 = blockIdx.y*128;
  int tid = threadIdx.x;
  int lane = tid & 63, w = tid >> 6;
  int wm = w >> 1, wn = w & 1;
  f32x4 acc[4][4] = {};
  int frow = lane & 15, fk = (lane >> 4)*8;
  for (int k0 = 0; k0 < K; k0 += 32) {
    #pragma unroll
    for (int p = 0; p < 2; ++p) {
      int task = tid + p*256;
      int row = task >> 2, c8 = (task & 3)*8;
      uint4 va = *(const uint4*)(Ab + (long)(m0+row)*lda + k0 + c8);
      uint4 vb = *(const uint4*)(Bb + (long)(n0+row)*ldb + k0 + c8);
      *(uint4*)&Al[row][c8] = va;
      *(uint4*)&Bl[row][c8] = vb;
    }
    __syncthreads();
    short8_t af[4], bfr[4];
    #pragma unroll
    for (int mi = 0; mi < 4; ++mi) af[mi]  = *(const short8_t*)&Al[wm*64 + mi*16 + frow][fk];
    #pragma unroll
    for (int ni = 0; ni < 4; ++ni) bfr[ni] = *(const short8_t*)&Bl[wn*64 + ni*16 + frow][fk];
    #pragma unroll
    for (int mi = 0; mi < 4; ++mi)
      #pragma unroll
      for (int ni = 0; ni < 4; ++ni)
        acc[mi][ni] = __builtin_amdgcn_mfma_f32_16x16x32_bf16(af[mi], bfr[ni], acc[mi][ni], 0, 0, 0);
    __syncthreads();
  }
  int rbase = (lane >> 4)*4;
  int col = lane & 15;
  #pragma unroll
  for (int mi = 0; mi < 4; ++mi)
    #pragma unroll
    for (int ni = 0; ni < 4; ++ni)
      #pragma unroll
      for (int i = 0; i < 4; ++i) {
        int gm = m0 + wm*64 + mi*16 + rbase + i;
        int gn = n0 + wn*64 + ni*16 + col;
        float vv = acc[mi][ni][i];
        if (outBf16) ((ushort*)Cout)[(long)bz*sC + (long)gm*ldc + gn] = f2bf(vv);
        else         ((float* )Cout)[(long)bz*sC + (long)gm*ldc + gn] = vv;
      }
}

// ---------------- SIMPLE scan: attention (q + scores + softmax + ctx), one block per b ----
__global__ __launch_bounds__(512)
void attn_step(const ushort* __restrict__ pkT, const ushort* __restrict__ Wq,
               const float* __restrict__ vatt, const float* __restrict__ hr,
               const ushort* __restrict__ ehb, ushort* __restrict__ packed, int t)
{
  int b = blockIdx.x, tid = threadIdx.x;
  __shared__ __align__(16) float h_s[512];
  __shared__ __align__(16) float q_s[512];
  __shared__ __align__(16) float al_s[512];
  __shared__ __align__(16) float red_s[8];
  h_s[tid] = hr[b*512 + tid];
  __syncthreads();
  // q[n] = sum_k h[k]*Wq[n,k]
  {
    const ushort* wrow = Wq + (long)tid*512;
    float acc = 0.f;
    for (int k = 0; k < 512; k += 8) {
      uint4 wv4 = *(const uint4*)(wrow + k);
      const ushort* wu = (const ushort*)&wv4;
      #pragma unroll
      for (int e = 0; e < 8; ++e) acc += h_s[k+e]*bf2f(wu[e]);
    }
    q_s[tid] = acc;
  }
  __syncthreads();
  // score[s=tid] = sum_h v[h]*tanh(pk[b,h,s] + q[h])
  float sc = 0.f;
  {
    const ushort* pkp = pkT + (long)b*262144 + tid;
    for (int h = 0; h < 512; ++h)
      sc += vatt[h]*ftanh(bf2f(pkp[(long)h*512]) + q_s[h]);
  }
  float e = __expf(sc);
  al_s[tid] = e;
  float r = e;
  #pragma unroll
  for (int off = 32; off; off >>= 1) r += __shfl_down(r, off);
  if ((tid & 63) == 0) red_s[tid >> 6] = r;
  __syncthreads();
  if (tid == 0) {
    float d = 0.f;
    #pragma unroll
    for (int i = 0; i < 8; ++i) d += red_s[i];
    red_s[0] = 1.f / d;
  }
  __syncthreads();
  float rds = red_s[0];
  float alpha = al_s[tid]*rds;
  __syncthreads();
  al_s[tid] = alpha;
  __syncthreads();
  // ctx[k] = sum_s alpha[s]*eh[b,s,k]
  for (int k = tid; k < 1024; k += 512) {
    const ushort* ep = ehb + (long)b*524288 + k;
    float acc = 0.f;
    for (int s = 0; s < 512; ++s)
      acc += al_s[s]*bf2f(ep[(long)s*1024]);
    packed[(long)(b*Tq + t)*KPACK + 640 + k] = f2bf(acc);
  }
}

// ---------------- SIMPLE gates: one thread per (b, gate-row) ----------------
__global__ __launch_bounds__(512)
void gates_step(const ushort* __restrict__ packed, const ushort* __restrict__ Wih,
                const ushort* __restrict__ Whh, const float* __restrict__ bsum,
                const float* __restrict__ hr, float* __restrict__ gates, int t)
{
  int b = blockIdx.x >> 2;
  int rr = (blockIdx.x & 3)*512 + threadIdx.x;
  __shared__ __align__(16) float x_s[1152];
  __shared__ __align__(16) float h_s[512];
  const ushort* xr = packed + (long)(b*Tq + t)*KPACK;
  for (int k = threadIdx.x; k < 1152; k += 512) {
    int src = (k < 128) ? k : (k + 512);    // ctx lives at packed[640 + (k-128)]
    x_s[k] = bf2f(xr[src]);
  }
  h_s[threadIdx.x] = hr[b*512 + threadIdx.x];
  __syncthreads();
  float g = bsum[rr];
  const ushort* wi = Wih + (long)rr*1152;
  for (int k = 0; k < 1152; k += 8) {
    uint4 wv4 = *(const uint4*)(wi + k);
    const ushort* wu = (const ushort*)&wv4;
    #pragma unroll
    for (int e = 0; e < 8; ++e) g += x_s[k+e]*bf2f(wu[e]);
  }
  const ushort* wh = Whh + (long)rr*512;
  for (int k = 0; k < 512; k += 8) {
    uint4 wv4 = *(const uint4*)(wh + k);
    const ushort* wu = (const ushort*)&wv4;
    #pragma unroll
    for (int e = 0; e < 8; ++e) g += h_s[k+e]*bf2f(wu[e]);
  }
  gates[(long)b*2048 + rr] = g;
}

// ---------------- SIMPLE LSTM pointwise (f32 outs) ----------------
__global__ __launch_bounds__(512)
void lstm_step(const float* __restrict__ gates, float* __restrict__ cws,
               float* __restrict__ hw, float* __restrict__ outs,
               ushort* __restrict__ packed, int t)
{
  int b = blockIdx.x, hd = threadIdx.x;
  const float* gb = gates + (long)b*2048;
  float gi = gb[hd], gf = gb[512+hd], gg = gb[1024+hd], go = gb[1536+hd];
  float co = cws[b*512+hd];
  float cn = fsig(gf)*co + fsig(gi)*ftanh(gg);
  float hn = fsig(go)*ftanh(cn);
  cws[b*512+hd] = cn;
  hw[b*512+hd] = hn;
  outs[(long)(b*Tq+t)*512 + hd] = hn;
  packed[(long)(b*Tq+t)*KPACK + 128 + hd] = f2bf(hn);
}

__global__ void epilogue_copy(const float* __restrict__ hb0, const float* __restrict__ cws,
                              float* __restrict__ dout){
  int idx = blockIdx.x*blockDim.x + threadIdx.x;
  if (idx < 32768) {
    dout[8388608 + idx] = hb0[idx];
    dout[8421376 + idx] = cws[idx];
  }
}

// ---------------- conditional diagnostics (fire only on anomaly) ----------------
__global__ void pb_init(unsigned* pb){ if (threadIdx.x < 16) pb[threadIdx.x] = 0u; }

__global__ void probe_outs(const float* __restrict__ outs, unsigned* pb){
  long i = (long)blockIdx.x*blockDim.x + threadIdx.x;
  long stride = (long)gridDim.x*blockDim.x;
  float m = 0.f; unsigned cnt = 0;
  for (; i < 8388608L; i += stride) {
    float a = fabsf(outs[i]);
    m = fmaxf(m, a);
    if (a >= 0.9f) ++cnt;
  }
  atomicMax(pb + 0, __float_as_uint(m));
  if (cnt) atomicAdd(pb + 1, cnt);
}

__global__ void probe_ctxall(const ushort* __restrict__ packed, unsigned* pb){
  long i = (long)blockIdx.x*blockDim.x + threadIdx.x;
  long stride = (long)gridDim.x*blockDim.x;
  float m = 0.f;
  for (; i < 16777216L; i += stride) {
    long bt = i >> 10; int kk = (int)(i & 1023);
    m = fmaxf(m, fabsf(bf2f(packed[bt*KPACK + 640 + kk])));
  }
  atomicMax(pb + 2, __float_as_uint(m));
}

// verify MFMA pkT against scalar recompute on a 16x16 patch of b=0
__global__ void probe_pkcheck(const ushort* __restrict__ pkT, const ushort* __restrict__ Wk,
                              const ushort* __restrict__ ehb, unsigned* pb){
  int h = threadIdx.x >> 4, s = threadIdx.x & 15;
  float acc = 0.f;
  for (int k = 0; k < 1024; ++k)
    acc += bf2f(Wk[h*1024 + k]) * bf2f(ehb[(long)s*1024 + k]);
  float got = bf2f(pkT[(long)h*512 + s]);
  atomicMax(pb + 3, __float_as_uint(fabsf(acc - got)));
}

__global__ void probe_encode2(const unsigned* pb, float* out){
  if (threadIdx.x != 0 || blockIdx.x != 0) return;
  unsigned cnt = pb[1];
  float cxm = __uint_as_float(pb[2]);
  float pkd = __uint_as_float(pb[3]);
  float code = 0.f;
  if      (pkd > 0.05f) code = 49152.f + fminf(pkd*512.f, 8000.f);
  else if (cxm > 1.5f)  code = 16384.f + fminf(cxm*256.f, 8000.f);
  else if (cnt > 0u)    code = 8192.f + fminf((float)cnt, 4000.f);
  if (code != 0.f) out[0] = code;
}

extern "C" void kernel_launch(void* const* d_in, const int* in_sizes, int n_in,
                              void* d_out, int out_size, void* d_ws, size_t ws_size,
                              hipStream_t stream)
{
  float* out = (float*)d_out;
  static const int expect[18] = {2097152,33554432,65536,65536,32768,16384,
                                 524288,262144,512,524288,512,524288,512,
                                 2359296,1048576,2048,2048,851968};
  if (n_in != 18 || out_size != 16842752) {
    bail_kernel<<<1, 256, 0, stream>>>(out, 33.0f); return;
  }
  for (int i = 0; i < 18; ++i) if (in_sizes[i] != expect[i]) {
    bail_kernel<<<1, 256, 0, stream>>>(out, 100.0f + i); return;
  }
  if (ws_size < 166207552ULL) { bail_kernel<<<1, 256, 0, stream>>>(out, 77.0f); return; }

  const float* trg  = (const float*)d_in[0];
  const float* eh   = (const float*)d_in[1];
  const float* efh  = (const float*)d_in[2];
  const float* efc  = (const float*)d_in[3];
  const float* Wk   = (const float*)d_in[6];
  const float* Wq   = (const float*)d_in[7];
  const float* v    = (const float*)d_in[8];
  const float* bhw  = (const float*)d_in[9];
  const float* bhb  = (const float*)d_in[10];
  const float* bcw  = (const float*)d_in[11];
  const float* bcb  = (const float*)d_in[12];
  const float* Wih  = (const float*)d_in[13];
  const float* Whh  = (const float*)d_in[14];
  const float* bih  = (const float*)d_in[15];
  const float* bhh  = (const float*)d_in[16];
  const float* Wpre = (const float*)d_in[17];
  char* ws = (char*)d_ws;

  ushort* ehb    = (ushort*)(ws + 0);
  ushort* pkT    = (ushort*)(ws + 67108864);
  ushort* packed = (ushort*)(ws + 100663296);
  ushort* Wk_b   = (ushort*)(ws + 155189248);
  ushort* Wq_b   = (ushort*)(ws + 156237824);
  ushort* Wih_b  = (ushort*)(ws + 156762112);
  ushort* Whh_b  = (ushort*)(ws + 161480704);
  ushort* Wpre_b = (ushort*)(ws + 163577856);
  float*  bsum   = (float*)(ws + 165281792);
  float*  hb0    = (float*)(ws + 165289984);
  float*  hb1    = (float*)(ws + 165421056);
  float*  cws    = (float*)(ws + 165552128);
  float*  gates  = (float*)(ws + 165683200);
  unsigned* pb   = (unsigned*)(ws + 166207488);

  pb_init<<<1, 64, 0, stream>>>(pb);

  auto cb = [&](const float* s, ushort* d, int n){
    int n4 = n/4;
    conv_bf16<<<(n4 + 255)/256, 256, 0, stream>>>(s, d, n4);
  };
  cb(eh,   ehb,   64*512*1024);
  cb(Wk,   Wk_b,  512*1024);
  cb(Wq,   Wq_b,  512*512);
  cb(Wih,  Wih_b, 2048*1152);
  cb(Whh,  Whh_b, 2048*512);
  cb(Wpre, Wpre_b,512*1664);
  pack_trg<<<(524288 + 255)/256, 256, 0, stream>>>(trg, packed, 524288);
  bsum_kernel<<<8, 256, 0, stream>>>(bih, bhh, bsum, 2048);
  bridge_kernel<<<64, 512, 0, stream>>>(efh, efc, bhw, bhb, bcw, bcb, hb0, cws);
  // proj_key^T[b][h][s] = sum_k Wk[h,k] * eh[b,s,k]   (MFMA, verified by probe_pkcheck)
  gemm_bt<<<dim3(4,4,64), 256, 0, stream>>>(Wk_b, 1024, 0L, ehb, 1024, 524288L,
                                            (void*)pkT, 512, 262144L, 1024, 1);

  for (int t = 0; t < 256; ++t) {
    const float* hr = (t & 1) ? hb1 : hb0;
    float*       hw = (t & 1) ? hb0 : hb1;
    attn_step <<<64,  512, 0, stream>>>(pkT, Wq_b, v, hr, ehb, packed, t);
    gates_step<<<256, 512, 0, stream>>>(packed, Wih_b, Whh_b, bsum, hr, gates, t);
    lstm_step <<<64,  512, 0, stream>>>(gates, cws, hw, out, packed, t);
  }

  epilogue_copy<<<128, 256, 0, stream>>>(hb0, cws, out);
  // pre[(b,t)][n] = sum_k packed[(b,t),k] * Wpre[n,k]  -> f32 output
  gemm_bt<<<dim3(128,4,1), 256, 0, stream>>>(packed, 1664, 0L, Wpre_b, 1664, 0L,
                                             (void*)(out + 8454144), 512, 0L, 1664, 0);

  // conditional diagnostics (no effect on a correct run)
  probe_pkcheck<<<1, 256, 0, stream>>>(pkT, Wk_b, ehb, pb);
  probe_ctxall<<<1024, 256, 0, stream>>>(packed, pb);
  probe_outs<<<1024, 256, 0, stream>>>(out, pb);
  probe_encode2<<<1, 64, 0, stream>>>(pb, out);
}

// Round 7
// 17339.165 us; speedup vs baseline: 2.4307x; 2.4307x over previous
//
#include <hip/hip_runtime.h>

#define Tq 256
#define Sq 512
#define Hq 512
#define H2q 1024
#define KPACK 1664   // trg(128) | outs(512) | ctx(1024)

typedef __attribute__((ext_vector_type(8))) short short8_t;
typedef __attribute__((ext_vector_type(4))) float f32x4;

__device__ __forceinline__ float bf2f(ushort u){ return __uint_as_float(((unsigned)u)<<16); }
__device__ __forceinline__ ushort f2bf(float f){
  unsigned u = __float_as_uint(f);
  u += 0x7FFFu + ((u>>16)&1u);
  return (ushort)(u>>16);
}
__device__ __forceinline__ float frcp(float x){ return __builtin_amdgcn_rcpf(x); }
__device__ __forceinline__ float ftanh(float x){
  x = fminf(fmaxf(x, -15.f), 15.f);
  float u = __expf(x + x);
  return (u - 1.f) * frcp(u + 1.f);
}
__device__ __forceinline__ float fsig(float x){
  return frcp(1.f + __expf(-x));
}

// ---------------- guard bail (f32 out) ----------------
__global__ void bail_kernel(float* out, float v){
  if (threadIdx.x < 256) out[threadIdx.x] = v;
}

// ---------------- conversion kernels ----------------
__global__ void conv_bf16(const float* __restrict__ src, ushort* __restrict__ dst, int n4){
  int idx = blockIdx.x*blockDim.x + threadIdx.x;
  if (idx >= n4) return;
  float4 v = ((const float4*)src)[idx];
  ushort4 o; o.x = f2bf(v.x); o.y = f2bf(v.y); o.z = f2bf(v.z); o.w = f2bf(v.w);
  ((ushort4*)dst)[idx] = o;
}

__global__ void pack_trg(const float* __restrict__ trg, ushort* __restrict__ packed, int n4){
  int idx = blockIdx.x*blockDim.x + threadIdx.x;
  if (idx >= n4) return;                 // n4 = B*T*E/4
  float4 v = ((const float4*)trg)[idx];
  int bt = idx >> 5, r = idx & 31;       // E/4 = 32
  ushort4 o; o.x = f2bf(v.x); o.y = f2bf(v.y); o.z = f2bf(v.z); o.w = f2bf(v.w);
  *(ushort4*)&packed[(long)bt*KPACK + r*4] = o;
}

__global__ void bsum_kernel(const float* __restrict__ a, const float* __restrict__ b,
                            float* __restrict__ o, int n){
  int idx = blockIdx.x*blockDim.x + threadIdx.x;
  if (idx < n) o[idx] = a[idx] + b[idx];
}

// ---------------- bridge ----------------
__global__ __launch_bounds__(512)
void bridge_kernel(const float* __restrict__ efh, const float* __restrict__ efc,
                   const float* __restrict__ bhw, const float* __restrict__ bhb,
                   const float* __restrict__ bcw, const float* __restrict__ bcb,
                   float* __restrict__ hb0, float* __restrict__ cws)
{
  int b = blockIdx.x, n = threadIdx.x;
  __shared__ __align__(16) float eh_l[1024];
  __shared__ __align__(16) float ec_l[1024];
  eh_l[n]       = efh[b*1024 + n];
  eh_l[n + 512] = efh[b*1024 + 512 + n];
  ec_l[n]       = efc[b*1024 + n];
  ec_l[n + 512] = efc[b*1024 + 512 + n];
  __syncthreads();
  const float4* wh = (const float4*)(bhw + (long)n*1024);
  const float4* wc = (const float4*)(bcw + (long)n*1024);
  float ah = bhb[n], ac = bcb[n];
  for (int i = 0; i < 256; ++i) {
    float4 w1 = wh[i]; float4 w2 = wc[i];
    const float* e1 = &eh_l[i*4]; const float* e2 = &ec_l[i*4];
    ah += w1.x*e1[0] + w1.y*e1[1] + w1.z*e1[2] + w1.w*e1[3];
    ac += w2.x*e2[0] + w2.y*e2[1] + w2.z*e2[2] + w2.w*e2[3];
  }
  hb0[b*512 + n] = ftanh(ah);
  cws[b*512 + n] = ftanh(ac);
}

// ---------------- MFMA BT-GEMM: C[m,n] = sum_k A[m,k]*Bt[n,k] ----------------
__global__ __launch_bounds__(256)
void gemm_bt(const ushort* __restrict__ A, int lda, long sA,
             const ushort* __restrict__ Bt, int ldb, long sB,
             void* __restrict__ Cout, int ldc, long sC, int K, int outBf16)
{
  __shared__ __align__(16) ushort Al[128][40];
  __shared__ __align__(16) ushort Bl[128][40];
  int bz = blockIdx.z;
  const ushort* Ab = A + (long)bz*sA;
  const ushort* Bb = Bt + (long)bz*sB;
  int m0 = blockIdx.x*128, n0 = blockIdx.y*128;
  int tid = threadIdx.x;
  int lane = tid & 63, w = tid >> 6;
  int wm = w >> 1, wn = w & 1;
  f32x4 acc[4][4] = {};
  int frow = lane & 15, fk = (lane >> 4)*8;
  for (int k0 = 0; k0 < K; k0 += 32) {
    #pragma unroll
    for (int p = 0; p < 2; ++p) {
      int task = tid + p*256;
      int row = task >> 2, c8 = (task & 3)*8;
      uint4 va = *(const uint4*)(Ab + (long)(m0+row)*lda + k0 + c8);
      uint4 vb = *(const uint4*)(Bb + (long)(n0+row)*ldb + k0 + c8);
      *(uint4*)&Al[row][c8] = va;
      *(uint4*)&Bl[row][c8] = vb;
    }
    __syncthreads();
    short8_t af[4], bfr[4];
    #pragma unroll
    for (int mi = 0; mi < 4; ++mi) af[mi]  = *(const short8_t*)&Al[wm*64 + mi*16 + frow][fk];
    #pragma unroll
    for (int ni = 0; ni < 4; ++ni) bfr[ni] = *(const short8_t*)&Bl[wn*64 + ni*16 + frow][fk];
    #pragma unroll
    for (int mi = 0; mi < 4; ++mi)
      #pragma unroll
      for (int ni = 0; ni < 4; ++ni)
        acc[mi][ni] = __builtin_amdgcn_mfma_f32_16x16x32_bf16(af[mi], bfr[ni], acc[mi][ni], 0, 0, 0);
    __syncthreads();
  }
  int rbase = (lane >> 4)*4;
  int col = lane & 15;
  #pragma unroll
  for (int mi = 0; mi < 4; ++mi)
    #pragma unroll
    for (int ni = 0; ni < 4; ++ni)
      #pragma unroll
      for (int i = 0; i < 4; ++i) {
        int gm = m0 + wm*64 + mi*16 + rbase + i;
        int gn = n0 + wn*64 + ni*16 + col;
        float vv = acc[mi][ni][i];
        if (outBf16) ((ushort*)Cout)[(long)bz*sC + (long)gm*ldc + gn] = f2bf(vv);
        else         ((float* )Cout)[(long)bz*sC + (long)gm*ldc + gn] = vv;
      }
}

// ---------------- scan phase A: q + score partials ----------------
__global__ __launch_bounds__(512)
void scanA(const ushort* __restrict__ pkT, const ushort* __restrict__ Wq,
           const float* __restrict__ vatt, const float* __restrict__ hr,
           float* __restrict__ spart)
{
  __shared__ __align__(16) float h_lds[512];
  __shared__ __align__(16) float v_lds[128];
  __shared__ __align__(16) float q_red[640];
  __shared__ __align__(16) float q_lds[128];
  int tid = threadIdx.x, blk = blockIdx.x;
  int ab_b = blk >> 2, ab_j = blk & 3;
  h_lds[tid] = hr[ab_b*Hq + tid];
  if (tid < 128) v_lds[tid] = vatt[ab_j*128 + tid];
  __syncthreads();
  int nl = tid >> 2, kq = tid & 3;
  const ushort* wrow = Wq + (long)(ab_j*128 + nl)*Hq + kq*128;
  float qacc = 0.f;
  #pragma unroll 4
  for (int i = 0; i < 16; ++i) {
    uint4 wv4 = *(const uint4*)(wrow + i*8);
    const ushort* wu = (const ushort*)&wv4;
    const float* hp = &h_lds[kq*128 + i*8];
    #pragma unroll
    for (int e = 0; e < 8; ++e) qacc += hp[e]*bf2f(wu[e]);
  }
  q_red[nl*5 + kq] = qacc;
  __syncthreads();
  if (tid < 128)
    q_lds[tid] = q_red[tid*5+0] + q_red[tid*5+1] + q_red[tid*5+2] + q_red[tid*5+3];
  __syncthreads();
  const ushort* pkp = pkT + (long)(ab_b*Hq + ab_j*128)*Sq + tid;
  float sacc = 0.f;
  #pragma unroll 4
  for (int hh = 0; hh < 128; ++hh) {
    float x = bf2f(pkp[(long)hh*Sq]) + q_lds[hh];
    sacc += v_lds[hh]*ftanh(x);
  }
  spart[((ab_b*4 + ab_j) << 9) + tid] = sacc;
}

// ---------------- scan phase B: softmax + ctx quarter ----------------
__global__ __launch_bounds__(512)
void scanB(int t, const ushort* __restrict__ ehb, const float* __restrict__ spart,
           ushort* __restrict__ packed)
{
  __shared__ __align__(16) float e_lds[512];
  __shared__ __align__(16) float red[8];
  __shared__ float denomv;
  __shared__ __align__(16) float c_red[512];
  int tid = threadIdx.x, blk = blockIdx.x;
  int ab_b = blk >> 2, ab_j = blk & 3;
  int lane = tid & 63, wv = tid >> 6;
  float sc = spart[(ab_b*4+0)*512 + tid] + spart[(ab_b*4+1)*512 + tid]
           + spart[(ab_b*4+2)*512 + tid] + spart[(ab_b*4+3)*512 + tid];
  float e = __expf(sc);
  e_lds[tid] = e;
  float r = e;
  #pragma unroll
  for (int off = 32; off; off >>= 1) r += __shfl_down(r, off);
  if (lane == 0) red[wv] = r;
  __syncthreads();
  if (tid == 0) {
    float d = 0.f;
    #pragma unroll
    for (int i = 0; i < 8; ++i) d += red[i];
    denomv = d;
  }
  __syncthreads();
  float rds = frcp(denomv);
  int klocal = tid & 255, sh = tid >> 8;
  const ushort* ep = ehb + (long)(ab_b*Sq + sh*256)*H2q + ab_j*256 + klocal;
  float cacc = 0.f;
  #pragma unroll 4
  for (int ss = 0; ss < 256; ++ss)
    cacc += e_lds[sh*256 + ss]*bf2f(ep[(long)ss*H2q]);
  c_red[sh*256 + klocal] = cacc;
  __syncthreads();
  if (tid < 256)
    packed[(long)(ab_b*Tq + t)*KPACK + 640 + ab_j*256 + tid]
        = f2bf((c_red[tid] + c_red[256 + tid])*rds);
}

// ---------------- scan phase C: gates GEMM + LSTM pointwise ----------------
__global__ __launch_bounds__(512)
void scanC(int t, ushort* packed,
           const ushort* __restrict__ Wih, const ushort* __restrict__ Whh,
           const float* __restrict__ bsum, const float* __restrict__ hr,
           float* __restrict__ hw, float* __restrict__ cws,
           float* __restrict__ outs)
{
  __shared__ __align__(16) float  x_lds[8*KPACK];
  __shared__ __align__(16) ushort W_lds[64*128];
  __shared__ __align__(16) float  redc[4096];
  __shared__ __align__(16) float  g_lds[512];
  int tid = threadIdx.x, blk = blockIdx.x;
  int lane = tid & 63, wv = tid >> 6;
  int c_bg = blk >> 5, c_rc = blk & 31;

  for (int task = tid; task < 8*144; task += 512) {
    int bb = task/144, c8 = task%144;
    int gb = c_bg*8 + bb;
    const ushort* src; int xk;
    if (c8 < 16) { src = packed + (long)(gb*Tq + t)*KPACK + c8*8;            xk = c8*8; }
    else         { src = packed + (long)(gb*Tq + t)*KPACK + 640 + (c8-16)*8; xk = 128 + (c8-16)*8; }
    uint4 vv = *(const uint4*)src;
    const ushort* uu = (const ushort*)&vv;
    #pragma unroll
    for (int e = 0; e < 8; ++e) x_lds[bb*KPACK + xk + e] = bf2f(uu[e]);
  }
  for (int task = tid; task < 8*512; task += 512) {
    int bb = task >> 9, kk = task & 511;
    x_lds[bb*KPACK + 1152 + kk] = hr[(c_bg*8 + bb)*Hq + kk];
  }
  float acc[8] = {};
  int rl = lane;
  int kq = wv;
  for (int kt = 0; kt < 13; ++kt) {
    __syncthreads();
    #pragma unroll
    for (int p = 0; p < 2; ++p) {
      int task = tid + p*512;
      int row = task >> 4, c8 = (task & 15)*8;
      int rr = (row >> 4)*512 + c_rc*16 + (row & 15);
      const ushort* wsrc = (kt < 9) ? (Wih + (long)rr*1152 + kt*128 + c8)
                                    : (Whh + (long)rr*512  + (kt-9)*128 + c8);
      uint4 wv4 = *(const uint4*)wsrc;
      unsigned bo = (unsigned)(row*256 + c8*2) ^ (unsigned)((row & 7) << 4);
      *(uint4*)((char*)W_lds + bo) = wv4;
    }
    __syncthreads();
    int kk = kq*16;
    int xbase = kt*128 + kk;
    #pragma unroll
    for (int c = 0; c < 2; ++c) {
      unsigned bo = (unsigned)(rl*256 + (kk + c*8)*2) ^ (unsigned)((rl & 7) << 4);
      uint4 wv4 = *(const uint4*)((const char*)W_lds + bo);
      const ushort* wu = (const ushort*)&wv4;
      float wf[8];
      #pragma unroll
      for (int e = 0; e < 8; ++e) wf[e] = bf2f(wu[e]);
      #pragma unroll
      for (int bb = 0; bb < 8; ++bb) {
        const float* xp = &x_lds[bb*KPACK + xbase + c*8];
        float4 x0 = *(const float4*)xp;
        float4 x1 = *(const float4*)(xp + 4);
        acc[bb] += wf[0]*x0.x + wf[1]*x0.y + wf[2]*x0.z + wf[3]*x0.w
                 + wf[4]*x1.x + wf[5]*x1.y + wf[6]*x1.z + wf[7]*x1.w;
      }
    }
  }
  __syncthreads();
  #pragma unroll
  for (int bb = 0; bb < 8; ++bb)
    redc[(kq*8 + bb)*64 + rl] = acc[bb];
  __syncthreads();
  {
    int rl2 = tid & 63, bb = tid >> 6;
    float gvv = bsum[(rl2 >> 4)*512 + c_rc*16 + (rl2 & 15)];
    #pragma unroll
    for (int q2 = 0; q2 < 8; ++q2) gvv += redc[(q2*8 + bb)*64 + rl2];
    g_lds[bb*64 + rl2] = gvv;
  }
  __syncthreads();
  if (tid < 128) {
    int bb = tid >> 4, i2 = tid & 15;
    int gb = c_bg*8 + bb;
    int hd = c_rc*16 + i2;
    float gi = g_lds[bb*64 +  0 + i2];
    float gf = g_lds[bb*64 + 16 + i2];
    float gg = g_lds[bb*64 + 32 + i2];
    float go = g_lds[bb*64 + 48 + i2];
    float co = cws[gb*Hq + hd];
    float cn = fsig(gf)*co + fsig(gi)*ftanh(gg);
    float hn = fsig(go)*ftanh(cn);
    cws[gb*Hq + hd] = cn;
    hw[gb*Hq + hd] = hn;
    outs[(long)(gb*Tq + t)*Hq + hd] = hn;
    packed[(long)(gb*Tq + t)*KPACK + 128 + hd] = f2bf(hn);
  }
}

__global__ void epilogue_copy(const float* __restrict__ hb0, const float* __restrict__ cws,
                              float* __restrict__ dout){
  int idx = blockIdx.x*blockDim.x + threadIdx.x;
  if (idx < 32768) {
    dout[8388608 + idx] = hb0[idx];
    dout[8421376 + idx] = cws[idx];
  }
}

extern "C" void kernel_launch(void* const* d_in, const int* in_sizes, int n_in,
                              void* d_out, int out_size, void* d_ws, size_t ws_size,
                              hipStream_t stream)
{
  float* out = (float*)d_out;
  static const int expect[18] = {2097152,33554432,65536,65536,32768,16384,
                                 524288,262144,512,524288,512,524288,512,
                                 2359296,1048576,2048,2048,851968};
  if (n_in != 18 || out_size != 16842752) {
    bail_kernel<<<1, 256, 0, stream>>>(out, 33.0f); return;
  }
  for (int i = 0; i < 18; ++i) if (in_sizes[i] != expect[i]) {
    bail_kernel<<<1, 256, 0, stream>>>(out, 100.0f + i); return;
  }
  if (ws_size < 166207552ULL) { bail_kernel<<<1, 256, 0, stream>>>(out, 77.0f); return; }

  const float* trg  = (const float*)d_in[0];
  const float* eh   = (const float*)d_in[1];
  const float* efh  = (const float*)d_in[2];
  const float* efc  = (const float*)d_in[3];
  const float* Wk   = (const float*)d_in[6];
  const float* Wq   = (const float*)d_in[7];
  const float* v    = (const float*)d_in[8];
  const float* bhw  = (const float*)d_in[9];
  const float* bhb  = (const float*)d_in[10];
  const float* bcw  = (const float*)d_in[11];
  const float* bcb  = (const float*)d_in[12];
  const float* Wih  = (const float*)d_in[13];
  const float* Whh  = (const float*)d_in[14];
  const float* bih  = (const float*)d_in[15];
  const float* bhh  = (const float*)d_in[16];
  const float* Wpre = (const float*)d_in[17];
  char* ws = (char*)d_ws;

  ushort* ehb    = (ushort*)(ws + 0);
  ushort* pkT    = (ushort*)(ws + 67108864);
  ushort* packed = (ushort*)(ws + 100663296);
  ushort* Wk_b   = (ushort*)(ws + 155189248);
  ushort* Wq_b   = (ushort*)(ws + 156237824);
  ushort* Wih_b  = (ushort*)(ws + 156762112);
  ushort* Whh_b  = (ushort*)(ws + 161480704);
  ushort* Wpre_b = (ushort*)(ws + 163577856);
  float*  bsum   = (float*)(ws + 165281792);
  float*  hb0    = (float*)(ws + 165289984);
  float*  hb1    = (float*)(ws + 165421056);
  float*  cws    = (float*)(ws + 165552128);
  float*  spart  = (float*)(ws + 165683200);

  auto cb = [&](const float* s, ushort* d, int n){
    int n4 = n/4;
    conv_bf16<<<(n4 + 255)/256, 256, 0, stream>>>(s, d, n4);
  };
  cb(eh,   ehb,   64*512*1024);
  cb(Wk,   Wk_b,  512*1024);
  cb(Wq,   Wq_b,  512*512);
  cb(Wih,  Wih_b, 2048*1152);
  cb(Whh,  Whh_b, 2048*512);
  cb(Wpre, Wpre_b,512*1664);
  pack_trg<<<(524288 + 255)/256, 256, 0, stream>>>(trg, packed, 524288);
  bsum_kernel<<<8, 256, 0, stream>>>(bih, bhh, bsum, 2048);
  bridge_kernel<<<64, 512, 0, stream>>>(efh, efc, bhw, bhb, bcw, bcb, hb0, cws);
  // proj_key^T[b][h][s] = sum_k Wk[h,k] * eh[b,s,k]
  gemm_bt<<<dim3(4,4,64), 256, 0, stream>>>(Wk_b, 1024, 0L, ehb, 1024, 524288L,
                                            (void*)pkT, 512, 262144L, 1024, 1);

  for (int t = 0; t < 256; ++t) {
    const float* hr = (t & 1) ? hb1 : hb0;
    float*       hw = (t & 1) ? hb0 : hb1;
    scanA<<<256, 512, 0, stream>>>(pkT, Wq_b, v, hr, spart);
    scanB<<<256, 512, 0, stream>>>(t, ehb, spart, packed);
    scanC<<<256, 512, 0, stream>>>(t, packed, Wih_b, Whh_b, bsum, hr, hw, cws, out);
  }

  epilogue_copy<<<128, 256, 0, stream>>>(hb0, cws, out);
  // pre[(b,t)][n] = sum_k packed[(b,t),k] * Wpre[n,k]  -> f32 output
  gemm_bt<<<dim3(128,4,1), 256, 0, stream>>>(packed, 1664, 0L, Wpre_b, 1664, 0L,
                                             (void*)(out + 8454144), 512, 0L, 1664, 0);
}